// Round 14
// baseline (292.045 us; speedup 1.0000x reference)
//
#include <hip/hip_runtime.h>
#include <hip/hip_bf16.h>
#include <math.h>

#define BDIM 4
#define VDIM 8
#define NDIM 256
#define CDIM 768
#define HDIM 12
#define DHE  64
#define C3   (3*CDIM)
#define ROWS (BDIM*VDIM*NDIM)
#define KEYS (VDIM*NDIM)   // 2048

typedef __attribute__((ext_vector_type(8))) short short8;   // 8 bf16 = 4 VGPR
typedef __attribute__((ext_vector_type(4))) float float4v;  // MFMA acc

// packed f32x2 -> bf16x2 (RNE) in ONE instruction — gfx950 v_cvt_pk_bf16_f32.
__device__ __forceinline__ unsigned int pk2(float a, float b) {
    unsigned int r;
    asm("v_cvt_pk_bf16_f32 %0, %1, %2" : "=v"(r) : "v"(a), "v"(b));
    return r;
}

// 8 fp32 (two float4) -> uint4 of 8 bf16
__device__ __forceinline__ uint4 pk8(float4 a, float4 b) {
    uint4 r;
    r.x = pk2(a.x, a.y); r.y = pk2(a.z, a.w);
    r.z = pk2(b.x, b.y); r.w = pk2(b.z, b.w);
    return r;
}

// async 16B global -> LDS (wave-uniform base + lane*16; lane-order == LDS order)
__device__ __forceinline__ void gld_lds16(const unsigned short* g, unsigned short* l) {
    __builtin_amdgcn_global_load_lds(
        (const __attribute__((address_space(1))) void*)g,
        (__attribute__((address_space(3))) void*)l, 16, 0, 0);
}

#define QSCALE 0.18033688f   // 0.125 * log2(e), folded into stored Q

// ---------------------------------------------------------------------------
// One-shot fp32 -> bf16 pre-cast of feats, w_qkv, w_out (memory-bound ~9us).
// ---------------------------------------------------------------------------
#define NA8 786432   // 8192*768/8
#define NW8 221184   // 2304*768/8
#define NO8 73728    //  768*768/8

__global__ __launch_bounds__(256) void cast_bf16_all(
    const float* __restrict__ fA, const float* __restrict__ fW,
    const float* __restrict__ fO,
    unsigned short* __restrict__ bA, unsigned short* __restrict__ bW,
    unsigned short* __restrict__ bO)
{
    const int gid = blockIdx.x * 256 + threadIdx.x;
    const float* src;
    unsigned short* dst;
    int idx;
    if (gid < NA8)            { src = fA; dst = bA; idx = gid; }
    else if (gid < NA8 + NW8) { src = fW; dst = bW; idx = gid - NA8; }
    else                      { src = fO; dst = bO; idx = gid - NA8 - NW8; }
    const float4* p = (const float4*)(src + (size_t)idx * 8);
    *(uint4*)(dst + (size_t)idx * 8) = pk8(p[0], p[1]);
}

// ---------------------------------------------------------------------------
// Fused QKV GEMM. BK=64 twin-buffer + XCD swizzle + Q pre-scale (unchanged).
// ---------------------------------------------------------------------------
__global__ __launch_bounds__(256) void gemm_qkv_mfma(
    const unsigned short* __restrict__ A,    // feats bf16 [8192][768]
    const unsigned short* __restrict__ W,    // w_qkv bf16 [2304][768]
    const float* __restrict__ bias,
    unsigned short* __restrict__ out,        // qkv [8192][2304] bf16 (Q,K only)
    unsigned short* __restrict__ vT)         // [4][12][64][2048] bf16
{
    __shared__ __attribute__((aligned(16))) unsigned short As[2][128][32];
    __shared__ __attribute__((aligned(16))) unsigned short Ws[2][128][32];
    const int t = threadIdx.x;
    const int wave = t >> 6, lane = t & 63;
    const int m = lane & 15, quad = lane >> 4;
    const int wr = (wave >> 1) * 64, wc = (wave & 1) * 64;

    const int lin = blockIdx.y * gridDim.x + blockIdx.x;
    const int cpx = (gridDim.x * gridDim.y) >> 3;
    const int swz = (lin & 7) * cpx + (lin >> 3);
    const int row0 = (swz / gridDim.x) * 128, col0 = (swz % gridDim.x) * 128;

    // staging: thread t owns row (t>>2), k-chunk (t&3)*8 -> LDS byte t*16
    const int sr = t >> 2, sk = (t & 3) * 8;
    const unsigned short* ag = &A[(size_t)(row0 + sr) * CDIM + sk];
    const unsigned short* wg = &W[(size_t)(col0 + sr) * CDIM + sk];

    float4v acc[4][4] = {};

    for (int k0 = 0; k0 < CDIM; k0 += 64) {
        #pragma unroll
        for (int ks = 0; ks < 2; ks++) {
            gld_lds16(ag + k0 + ks * 32, &As[ks][sr][sk]);
            gld_lds16(ag + (size_t)64 * CDIM + k0 + ks * 32, &As[ks][64 + sr][sk]);
            gld_lds16(wg + k0 + ks * 32, &Ws[ks][sr][sk]);
            gld_lds16(wg + (size_t)64 * CDIM + k0 + ks * 32, &Ws[ks][64 + sr][sk]);
        }
        __syncthreads();
        #pragma unroll
        for (int ks = 0; ks < 2; ks++) {
            short8 a[4], b[4];
            #pragma unroll
            for (int rt = 0; rt < 4; rt++)
                a[rt] = *(const short8*)&As[ks][wr + rt * 16 + m][quad * 8];
            #pragma unroll
            for (int ct = 0; ct < 4; ct++)
                b[ct] = *(const short8*)&Ws[ks][wc + ct * 16 + m][quad * 8];
            #pragma unroll
            for (int rt = 0; rt < 4; rt++)
                #pragma unroll
                for (int ct = 0; ct < 4; ct++)
                    acc[rt][ct] = __builtin_amdgcn_mfma_f32_16x16x32_bf16(
                        a[rt], b[ct], acc[rt][ct], 0, 0, 0);
        }
        __syncthreads();
    }

    if (col0 < 2 * CDIM) {
        // Q/K epilogue -> qkv (Q blocks pre-scaled by QSCALE; attn does exp2(s))
        const float qs = (col0 < CDIM) ? QSCALE : 1.0f;
        #pragma unroll
        for (int ct = 0; ct < 4; ct++) {
            const int col = col0 + wc + ct * 16 + m;
            const float bv = bias[col];
            #pragma unroll
            for (int rt = 0; rt < 4; rt++) {
                const size_t row = (size_t)row0 + wr + rt * 16 + quad * 4;
                const unsigned u01 = pk2((acc[rt][ct][0] + bv) * qs,
                                         (acc[rt][ct][1] + bv) * qs);
                const unsigned u23 = pk2((acc[rt][ct][2] + bv) * qs,
                                         (acc[rt][ct][3] + bv) * qs);
                out[(row + 0) * C3 + col] = (unsigned short)u01;
                out[(row + 1) * C3 + col] = (unsigned short)(u01 >> 16);
                out[(row + 2) * C3 + col] = (unsigned short)u23;
                out[(row + 3) * C3 + col] = (unsigned short)(u23 >> 16);
            }
        }
    } else {
        // V epilogue -> transposed vT (4 consecutive keys per lane -> 8B)
        #pragma unroll
        for (int ct = 0; ct < 4; ct++) {
            const int vcol = col0 + wc + ct * 16 + m - 2 * CDIM;
            const int h = vcol >> 6, d = vcol & 63;
            const float bv = bias[col0 + wc + ct * 16 + m];
            #pragma unroll
            for (int rt = 0; rt < 4; rt++) {
                const int row = row0 + wr + rt * 16 + quad * 4;
                const int bidx = row >> 11, key = row & 2047;
                uint2 pv2;
                pv2.x = pk2(acc[rt][ct][0] + bv, acc[rt][ct][1] + bv);
                pv2.y = pk2(acc[rt][ct][2] + bv, acc[rt][ct][3] + bv);
                *(uint2*)&vT[((size_t)(bidx * HDIM + h) * DHE + d) * KEYS + key] = pv2;
            }
        }
    }
}

// ---------------------------------------------------------------------------
// MFMA flash attention. R14 = R12 known-good Vs/Ps layouts (16B-aligned,
// XOR-swizzled Vs, Ps stride 144B) + K moved from LDS to per-lane GLOBAL
// register frags (kfA/kfB ping-pong, prefetched two windows ahead).
// R13 post-mortem: the pad-to-70-shorts layout broke 16B alignment of every
// ds b128 access (rows at odd*140B) -> NaN. K global frag addresses are all
// 16B-aligned (row stride 4608B, offsets ks*64B + quad*16B), so only the K
// change lands this round. Removes per window: 8 ds_read_b128 + 2
// ds_write_b128 + K staging; dedupes 4x cross-wave K reads into XCD-local
// L2 (lines are contiguous 64B per (m,ks)). LDS 51.2 -> 34.4KB.
// ---------------------------------------------------------------------------
__global__ __launch_bounds__(256, 3) void attn_mfma(
    const unsigned short* __restrict__ qkv,  // [8192][2304] bf16 (Qs,K)
    const unsigned short* __restrict__ vT,   // [4][12][64][2048] bf16
    const int* __restrict__ is_ref,
    unsigned short* __restrict__ ctx)        // [8192][768] bf16
{
    const int g = blockIdx.x;
    const int myx = g & 7, cuu = (g >> 3) & 31, round = g >> 8;
    const int j = round * 32 + ((round & 1) ? (31 - cuu) : cuu); // slot 0..95

    // ---- per-batch ref info ----
    int rmask[4], r4[4];
    #pragma unroll
    for (int bb = 0; bb < 4; bb++) {
        int mask = 0;
        #pragma unroll
        for (int w = 0; w < VDIM; w++)
            if (is_ref[bb * VDIM + w] != 0) mask |= 1 << w;
        rmask[bb] = mask; r4[bb] = __popc(mask);
    }
    // ---- 1. sort batches desc by weight r(8-r) ----
    int ord[4] = {0, 1, 2, 3};
    #pragma unroll
    for (int i = 0; i < 3; i++)
        #pragma unroll
        for (int k = 0; k < 3 - i; k++) {
            const int wa = r4[ord[k]] * (8 - r4[ord[k]]);
            const int wb = r4[ord[k + 1]] * (8 - r4[ord[k + 1]]);
            if (wb > wa) { int tmp = ord[k]; ord[k] = ord[k + 1]; ord[k + 1] = tmp; }
        }
    // ---- 2. snake-deal 48 grps to 8 XCDs; collect my 6 (Gb, Gh) ----
    int Gb[6], Gh[6], ng = 0;
    for (int p = 0; p < 48; p++) {
        const int row = p >> 3, col = p & 7;
        const int x = (row & 1) ? (7 - col) : col;
        if (x == myx) { Gb[ng] = ord[p / 12]; Gh[ng] = p % 12; ng++; }
    }
    // ---- 3. class walk: find j-th task of this XCD (LPT order) ----
    int b = 0, h = 0, half = 0, v = 0, Lsel = 0;
    {
        int jj = j;
        bool found = false;
        for (int o = 8; o >= 0 && !found; o--) {
            for (int gi = 0; gi < 6 && !found; gi++) {
                const int b2 = Gb[gi], r2 = r4[b2];
                const int nv_o = ((8 - r2) == o ? r2 : 0) + (r2 == o ? (8 - r2) : 0);
                const int cnt = 2 * nv_o;
                if (cnt > 0 && jj < cnt) {
                    b = b2; h = Gh[gi]; Lsel = o;
                    half = jj / nv_o;
                    int pos = jj % nv_o;
                    int S = (((8 - r2) == o) ? rmask[b2] : 0)
                          | ((r2 == o) ? ((~rmask[b2]) & 0xff) : 0);
                    for (int vv = 0; vv < 8; vv++)
                        if ((S >> vv) & 1) { if (pos == 0) { v = vv; break; } pos--; }
                    found = true;
                } else jj -= cnt;
            }
        }
    }
    // ------------------------------------------------------

    const int t = threadIdx.x, wave = t >> 6, lane = t & 63;
    const int m = lane & 15, quad = lane >> 4;
    const int n0 = half * 128 + wave * 32;

    __shared__ unsigned short Vs[2][64][64]; // [buf][dim][key], kg' = kg^(dim&7)
    __shared__ unsigned short Ps[4][32][72]; // [wave][query][64-key chunk]

    const int my_ref = (rmask[b] >> v) & 1;
    const unsigned amask = my_ref ? (unsigned)((~rmask[b]) & 0xff)
                                  : (unsigned)rmask[b];
    const int nC = 4 * Lsel;                 // 64-key chunks (multiple of 4)

    // packed view list: nibble i = i-th set bit of amask
    unsigned vpack = 0;
    {
        unsigned rm = amask; int pi = 0;
        while (rm) { vpack |= (unsigned)(__builtin_ffs((int)rm) - 1) << (4 * pi);
                     rm &= rm - 1; pi++; }
    }

    // Q B-frags: B[n=query=m][k=quad*8+j], two 32-dim K-steps (Q pre-scaled)
    short8 aq[2][2];
    #pragma unroll
    for (int qt = 0; qt < 2; qt++) {
        const size_t row = (size_t)((b * VDIM + v) * NDIM) + n0 + qt * 16 + m;
        #pragma unroll
        for (int ks = 0; ks < 2; ks++)
            aq[qt][ks] = *(const short8*)&qkv[row * C3 + h * DHE + ks * 32 + quad * 8];
    }

    float rs[2] = {0.f, 0.f};     // per-lane l partial, query = qt*16 + m
    float4v O[2][4] = {};

    // V staging coords: 64 dims x 4 threads, 2x16B per thread
    const int s_row = t >> 2;                  // dim, 0..63
    const int s_g   = (t & 3) * 2;             // first 8-short group, 0..7

    const unsigned short* vTb = vT + (size_t)(b * HDIM + h) * DHE * KEYS;
    const unsigned short* qkb = qkv + (size_t)(b * VDIM) * NDIM * C3 + CDIM + h * DHE;

    uint4 vreg[2];
    uint4 kfA[4][2], kfB[4][2];   // K A-frags, ping-pong (static idx only)

    // chunk c -> view vpack nibble (c>>2), keybase (c&3)*64 within view
    #define LOADV(c)                                                           \
        {                                                                      \
            const int w_ = (int)((vpack >> (((c) >> 2) * 4)) & 15);            \
            const int kb_ = ((c) & 3) * 64;                                    \
            const unsigned short* vp = vTb + (size_t)s_row * KEYS + w_ * NDIM + kb_; \
            vreg[0] = *(const uint4*)&vp[(s_g + 0) * 8];                       \
            vreg[1] = *(const uint4*)&vp[(s_g + 1) * 8];                       \
        }
    #define WRITEV(buf)                                                        \
        {                                                                      \
            *(uint4*)&Vs[buf][s_row][((s_g + 0) ^ (s_row & 7)) * 8] = vreg[0]; \
            *(uint4*)&Vs[buf][s_row][((s_g + 1) ^ (s_row & 7)) * 8] = vreg[1]; \
        }
    // per-lane K A-frag loads: kf[nt][ks] = K[key=base+nt*16+m][dim ks*32+quad*8..]
    #define LOADKF(c, kf)                                                      \
        {                                                                      \
            const int w_ = (int)((vpack >> (((c) >> 2) * 4)) & 15);            \
            const unsigned short* kp = qkb                                     \
                + (size_t)(w_ * NDIM + ((c) & 3) * 64) * C3;                   \
            _Pragma("unroll")                                                  \
            for (int nt = 0; nt < 4; nt++)                                     \
                _Pragma("unroll")                                              \
                for (int ks = 0; ks < 2; ks++)                                 \
                    kf[nt][ks] = *(const uint4*)&kp[(size_t)(nt * 16 + m) * C3 \
                                                    + ks * 32 + quad * 8];     \
        }
    // one 64-key window: compute chunk c with K-frags `cur`, then refill
    // `cur` with K(c+2) for two windows ahead.
    #define WINDOW(c, cur)                                                     \
        {                                                                      \
            const int buf = (c) & 1;                                           \
            __syncthreads();                                                   \
            if ((c) + 1 < nC) {                                                \
                WRITEV(buf ^ 1);                                               \
                if ((c) + 2 < nC) LOADV((c) + 2);                              \
            }                                                                  \
            _Pragma("unroll")                                                  \
            for (int kt = 0; kt < 4; kt++) {                                   \
                const short8 bk0 = __builtin_bit_cast(short8, cur[kt][0]);     \
                const short8 bk1 = __builtin_bit_cast(short8, cur[kt][1]);     \
                _Pragma("unroll")                                              \
                for (int qt = 0; qt < 2; qt++) {                               \
                    float4v s = {};                                            \
                    s = __builtin_amdgcn_mfma_f32_16x16x32_bf16(bk0, aq[qt][0], s, 0, 0, 0); \
                    s = __builtin_amdgcn_mfma_f32_16x16x32_bf16(bk1, aq[qt][1], s, 0, 0, 0); \
                    const float p0 = __builtin_amdgcn_exp2f(s[0]);             \
                    const float p1 = __builtin_amdgcn_exp2f(s[1]);             \
                    const float p2 = __builtin_amdgcn_exp2f(s[2]);             \
                    const float p3 = __builtin_amdgcn_exp2f(s[3]);             \
                    rs[qt] += (p0 + p1) + (p2 + p3);                           \
                    uint2 pw;                                                  \
                    pw.x = pk2(p0, p1);                                        \
                    pw.y = pk2(p2, p3);                                        \
                    *(uint2*)&Ps[wave][qt * 16 + m][kt * 16 + quad * 4] = pw;  \
                }                                                              \
            }                                                                  \
            if ((c) + 2 < nC) LOADKF((c) + 2, cur);                            \
            _Pragma("unroll")                                                  \
            for (int kk = 0; kk < 2; kk++) {                                   \
                const short8 ap0 = *(const short8*)&Ps[wave][m][kk * 32 + quad * 8]; \
                const short8 ap1 = *(const short8*)&Ps[wave][16 + m][kk * 32 + quad * 8]; \
                _Pragma("unroll")                                              \
                for (int ct = 0; ct < 4; ct++) {                               \
                    const short8 bv = *(const short8*)&Vs[buf][ct * 16 + m]    \
                        [((kk * 4 + quad) ^ (m & 7)) * 8];                     \
                    O[0][ct] = __builtin_amdgcn_mfma_f32_16x16x32_bf16(ap0, bv, O[0][ct], 0, 0, 0); \
                    O[1][ct] = __builtin_amdgcn_mfma_f32_16x16x32_bf16(ap1, bv, O[1][ct], 0, 0, 0); \
                }                                                              \
            }                                                                  \
        }

    if (nC > 0) {
        LOADV(0);
        WRITEV(0);                 // no prior readers; pre-barrier write ok
        if (nC > 1) LOADV(1);
        LOADKF(0, kfA);
        if (nC > 1) LOADKF(1, kfB);
    }

    for (int c = 0; c < nC; c += 2) {   // nC is a multiple of 4
        WINDOW(c, kfA);
        WINDOW(c + 1, kfB);
    }
    #undef LOADV
    #undef WRITEV
    #undef LOADKF
    #undef WINDOW

    // final: reduce l across the 4 quad-copies, broadcast to O rows, write
    #pragma unroll
    for (int qt = 0; qt < 2; qt++) {
        float x = rs[qt];
        x += __shfl_xor(x, 16, 64);
        x += __shfl_xor(x, 32, 64);
        const float inv = (x > 0.f) ? 1.f / x : 0.f;   // query = qt*16 + m
        float invq[4];
        #pragma unroll
        for (int r = 0; r < 4; r++)
            invq[r] = __shfl(inv, quad * 4 + r, 64);   // query = qt*16+quad*4+r
        const size_t rowg = (size_t)((b * VDIM + v) * NDIM) + n0 + qt * 16 + quad * 4;
        #pragma unroll
        for (int ct = 0; ct < 4; ct++) {
            const int cc = h * DHE + ct * 16 + m;
            const unsigned u01 = pk2(O[qt][ct][0] * invq[0], O[qt][ct][1] * invq[1]);
            const unsigned u23 = pk2(O[qt][ct][2] * invq[2], O[qt][ct][3] * invq[3]);
            ctx[(rowg + 0) * CDIM + cc] = (unsigned short)u01;
            ctx[(rowg + 1) * CDIM + cc] = (unsigned short)(u01 >> 16);
            ctx[(rowg + 2) * CDIM + cc] = (unsigned short)u23;
            ctx[(rowg + 3) * CDIM + cc] = (unsigned short)(u23 >> 16);
        }
    }
}

// ---------------------------------------------------------------------------
// Out-proj GEMM. BK=64 twin-buffer + XCD swizzle; fp32 out + passthrough.
// ---------------------------------------------------------------------------
__global__ __launch_bounds__(256) void gemm_out_mfma(
    const unsigned short* __restrict__ A,   // ctx_b [8192][768] bf16
    const unsigned short* __restrict__ W,   // w_out bf16 [768][768]
    const float* __restrict__ bias,
    const float* __restrict__ feats,
    const int* __restrict__ is_ref,
    float* __restrict__ out)                // [8192][768] fp32
{
    __shared__ __attribute__((aligned(16))) unsigned short As[2][128][32];
    __shared__ __attribute__((aligned(16))) unsigned short Ws[2][128][32];
    const int t = threadIdx.x;
    const int wave = t >> 6, lane = t & 63;
    const int m = lane & 15, quad = lane >> 4;
    const int wr = (wave >> 1) * 64, wc = (wave & 1) * 64;

    const int lin = blockIdx.y * gridDim.x + blockIdx.x;
    const int cpx = (gridDim.x * gridDim.y) >> 3;
    const int swz = (lin & 7) * cpx + (lin >> 3);
    const int row0 = (swz / gridDim.x) * 128, col0 = (swz % gridDim.x) * 128;

    const int sr = t >> 2, sk = (t & 3) * 8;
    const unsigned short* ag = &A[(size_t)(row0 + sr) * CDIM + sk];
    const unsigned short* wg = &W[(size_t)(col0 + sr) * CDIM + sk];

    float4v acc[4][4] = {};

    for (int k0 = 0; k0 < CDIM; k0 += 64) {
        #pragma unroll
        for (int ks = 0; ks < 2; ks++) {
            gld_lds16(ag + k0 + ks * 32, &As[ks][sr][sk]);
            gld_lds16(ag + (size_t)64 * CDIM + k0 + ks * 32, &As[ks][64 + sr][sk]);
            gld_lds16(wg + k0 + ks * 32, &Ws[ks][sr][sk]);
            gld_lds16(wg + (size_t)64 * CDIM + k0 + ks * 32, &Ws[ks][64 + sr][sk]);
        }
        __syncthreads();
        #pragma unroll
        for (int ks = 0; ks < 2; ks++) {
            short8 a[4], b[4];
            #pragma unroll
            for (int rt = 0; rt < 4; rt++)
                a[rt] = *(const short8*)&As[ks][wr + rt * 16 + m][quad * 8];
            #pragma unroll
            for (int ct = 0; ct < 4; ct++)
                b[ct] = *(const short8*)&Ws[ks][wc + ct * 16 + m][quad * 8];
            #pragma unroll
            for (int rt = 0; rt < 4; rt++)
                #pragma unroll
                for (int ct = 0; ct < 4; ct++)
                    acc[rt][ct] = __builtin_amdgcn_mfma_f32_16x16x32_bf16(
                        a[rt], b[ct], acc[rt][ct], 0, 0, 0);
        }
        __syncthreads();
    }

    const int bidx = row0 / (VDIM * NDIM);
    const int vidx = (row0 / NDIM) % VDIM;
    const int my = is_ref[bidx * VDIM + vidx];
    bool has = false;
    #pragma unroll
    for (int w = 0; w < VDIM; w++) has = has || (is_ref[bidx * VDIM + w] != my);

    #pragma unroll
    for (int ct = 0; ct < 4; ct++) {
        const int col = col0 + wc + ct * 16 + m;
        const float bv = bias[col];
        #pragma unroll
        for (int rt = 0; rt < 4; rt++) {
            const size_t row = (size_t)row0 + wr + rt * 16 + quad * 4;
            #pragma unroll
            for (int r = 0; r < 4; r++) {
                float o = acc[rt][ct][r] + bv;
                if (!has) o = feats[(row + r) * CDIM + col];
                out[(row + r) * CDIM + col] = o;
            }
        }
    }
}

extern "C" void kernel_launch(void* const* d_in, const int* in_sizes, int n_in,
                              void* d_out, int out_size, void* d_ws, size_t ws_size,
                              hipStream_t stream) {
    const float* feats = (const float*)d_in[0];
    const int*   is_ref = (const int*)d_in[1];
    const float* w_qkv = (const float*)d_in[2];
    const float* b_qkv = (const float*)d_in[3];
    const float* w_out = (const float*)d_in[4];
    const float* b_out = (const float*)d_in[5];
    float* out = (float*)d_out;

    unsigned short* qkv_b = (unsigned short*)d_ws;                 // 8192x2304
    unsigned short* vT    = qkv_b + (size_t)ROWS * C3;             // 4x12x64x2048
    unsigned short* ctx_b = vT + (size_t)BDIM * HDIM * DHE * KEYS; // 8192x768
    unsigned short* A_bf  = ctx_b + (size_t)ROWS * CDIM;           // 8192x768
    unsigned short* Wq_bf = A_bf + (size_t)ROWS * CDIM;            // 2304x768
    unsigned short* Wo_bf = Wq_bf + (size_t)C3 * CDIM;             // 768x768

    cast_bf16_all<<<dim3((NA8 + NW8 + NO8) / 256), 256, 0, stream>>>(
        feats, w_qkv, w_out, A_bf, Wq_bf, Wo_bf);

    dim3 g1(C3 / 128, ROWS / 128);                                 // 18 x 64
    gemm_qkv_mfma<<<g1, 256, 0, stream>>>(A_bf, Wq_bf, b_qkv, qkv_b, vT);

    attn_mfma<<<dim3(768), 256, 0, stream>>>(qkv_b, vT, is_ref, ctx_b);

    dim3 g3(CDIM / 128, ROWS / 128);                               // 6 x 64
    gemm_out_mfma<<<g3, 256, 0, stream>>>(ctx_b, Wo_bf, b_out, feats, is_ref, out);
    (void)in_sizes; (void)n_in; (void)out_size; (void)ws_size;
}

// Round 15
// 223.198 us; speedup vs baseline: 1.3085x; 1.3085x over previous
//
#include <hip/hip_runtime.h>
#include <hip/hip_bf16.h>
#include <math.h>

#define BDIM 4
#define VDIM 8
#define NDIM 256
#define CDIM 768
#define HDIM 12
#define DHE  64
#define C3   (3*CDIM)
#define ROWS (BDIM*VDIM*NDIM)
#define KEYS (VDIM*NDIM)   // 2048

typedef __attribute__((ext_vector_type(8))) short short8;   // 8 bf16 = 4 VGPR
typedef __attribute__((ext_vector_type(4))) float float4v;  // MFMA acc

// packed f32x2 -> bf16x2 (RNE) in ONE instruction — gfx950 v_cvt_pk_bf16_f32.
__device__ __forceinline__ unsigned int pk2(float a, float b) {
    unsigned int r;
    asm("v_cvt_pk_bf16_f32 %0, %1, %2" : "=v"(r) : "v"(a), "v"(b));
    return r;
}

// 8 fp32 (two float4) -> uint4 of 8 bf16
__device__ __forceinline__ uint4 pk8(float4 a, float4 b) {
    uint4 r;
    r.x = pk2(a.x, a.y); r.y = pk2(a.z, a.w);
    r.z = pk2(b.x, b.y); r.w = pk2(b.z, b.w);
    return r;
}

// async 16B global -> LDS (wave-uniform base + lane*16; lane-order == LDS order)
__device__ __forceinline__ void gld_lds16(const unsigned short* g, unsigned short* l) {
    __builtin_amdgcn_global_load_lds(
        (const __attribute__((address_space(1))) void*)g,
        (__attribute__((address_space(3))) void*)l, 16, 0, 0);
}

#define QSCALE 0.18033688f   // 0.125 * log2(e), folded into stored Q

// ---------------------------------------------------------------------------
// One-shot fp32 -> bf16 pre-cast of feats, w_qkv, w_out (memory-bound ~9us).
// ---------------------------------------------------------------------------
#define NA8 786432   // 8192*768/8
#define NW8 221184   // 2304*768/8
#define NO8 73728    //  768*768/8

__global__ __launch_bounds__(256) void cast_bf16_all(
    const float* __restrict__ fA, const float* __restrict__ fW,
    const float* __restrict__ fO,
    unsigned short* __restrict__ bA, unsigned short* __restrict__ bW,
    unsigned short* __restrict__ bO)
{
    const int gid = blockIdx.x * 256 + threadIdx.x;
    const float* src;
    unsigned short* dst;
    int idx;
    if (gid < NA8)            { src = fA; dst = bA; idx = gid; }
    else if (gid < NA8 + NW8) { src = fW; dst = bW; idx = gid - NA8; }
    else                      { src = fO; dst = bO; idx = gid - NA8 - NW8; }
    const float4* p = (const float4*)(src + (size_t)idx * 8);
    *(uint4*)(dst + (size_t)idx * 8) = pk8(p[0], p[1]);
}

// ---------------------------------------------------------------------------
// Fused QKV GEMM. BK=64 twin-buffer + XCD swizzle + Q pre-scale.
// ---------------------------------------------------------------------------
__global__ __launch_bounds__(256) void gemm_qkv_mfma(
    const unsigned short* __restrict__ A,    // feats bf16 [8192][768]
    const unsigned short* __restrict__ W,    // w_qkv bf16 [2304][768]
    const float* __restrict__ bias,
    unsigned short* __restrict__ out,        // qkv [8192][2304] bf16 (Q,K only)
    unsigned short* __restrict__ vT)         // [4][12][64][2048] bf16
{
    __shared__ __attribute__((aligned(16))) unsigned short As[2][128][32];
    __shared__ __attribute__((aligned(16))) unsigned short Ws[2][128][32];
    const int t = threadIdx.x;
    const int wave = t >> 6, lane = t & 63;
    const int m = lane & 15, quad = lane >> 4;
    const int wr = (wave >> 1) * 64, wc = (wave & 1) * 64;

    const int lin = blockIdx.y * gridDim.x + blockIdx.x;
    const int cpx = (gridDim.x * gridDim.y) >> 3;
    const int swz = (lin & 7) * cpx + (lin >> 3);
    const int row0 = (swz / gridDim.x) * 128, col0 = (swz % gridDim.x) * 128;

    // staging: thread t owns row (t>>2), k-chunk (t&3)*8 -> LDS byte t*16
    const int sr = t >> 2, sk = (t & 3) * 8;
    const unsigned short* ag = &A[(size_t)(row0 + sr) * CDIM + sk];
    const unsigned short* wg = &W[(size_t)(col0 + sr) * CDIM + sk];

    float4v acc[4][4] = {};

    for (int k0 = 0; k0 < CDIM; k0 += 64) {
        #pragma unroll
        for (int ks = 0; ks < 2; ks++) {
            gld_lds16(ag + k0 + ks * 32, &As[ks][sr][sk]);
            gld_lds16(ag + (size_t)64 * CDIM + k0 + ks * 32, &As[ks][64 + sr][sk]);
            gld_lds16(wg + k0 + ks * 32, &Ws[ks][sr][sk]);
            gld_lds16(wg + (size_t)64 * CDIM + k0 + ks * 32, &Ws[ks][64 + sr][sk]);
        }
        __syncthreads();
        #pragma unroll
        for (int ks = 0; ks < 2; ks++) {
            short8 a[4], b[4];
            #pragma unroll
            for (int rt = 0; rt < 4; rt++)
                a[rt] = *(const short8*)&As[ks][wr + rt * 16 + m][quad * 8];
            #pragma unroll
            for (int ct = 0; ct < 4; ct++)
                b[ct] = *(const short8*)&Ws[ks][wc + ct * 16 + m][quad * 8];
            #pragma unroll
            for (int rt = 0; rt < 4; rt++)
                #pragma unroll
                for (int ct = 0; ct < 4; ct++)
                    acc[rt][ct] = __builtin_amdgcn_mfma_f32_16x16x32_bf16(
                        a[rt], b[ct], acc[rt][ct], 0, 0, 0);
        }
        __syncthreads();
    }

    if (col0 < 2 * CDIM) {
        // Q/K epilogue -> qkv (Q blocks pre-scaled by QSCALE; attn does exp2(s))
        const float qs = (col0 < CDIM) ? QSCALE : 1.0f;
        #pragma unroll
        for (int ct = 0; ct < 4; ct++) {
            const int col = col0 + wc + ct * 16 + m;
            const float bv = bias[col];
            #pragma unroll
            for (int rt = 0; rt < 4; rt++) {
                const size_t row = (size_t)row0 + wr + rt * 16 + quad * 4;
                const unsigned u01 = pk2((acc[rt][ct][0] + bv) * qs,
                                         (acc[rt][ct][1] + bv) * qs);
                const unsigned u23 = pk2((acc[rt][ct][2] + bv) * qs,
                                         (acc[rt][ct][3] + bv) * qs);
                out[(row + 0) * C3 + col] = (unsigned short)u01;
                out[(row + 1) * C3 + col] = (unsigned short)(u01 >> 16);
                out[(row + 2) * C3 + col] = (unsigned short)u23;
                out[(row + 3) * C3 + col] = (unsigned short)(u23 >> 16);
            }
        }
    } else {
        // V epilogue -> transposed vT (4 consecutive keys per lane -> 8B)
        #pragma unroll
        for (int ct = 0; ct < 4; ct++) {
            const int vcol = col0 + wc + ct * 16 + m - 2 * CDIM;
            const int h = vcol >> 6, d = vcol & 63;
            const float bv = bias[col0 + wc + ct * 16 + m];
            #pragma unroll
            for (int rt = 0; rt < 4; rt++) {
                const int row = row0 + wr + rt * 16 + quad * 4;
                const int bidx = row >> 11, key = row & 2047;
                uint2 pv2;
                pv2.x = pk2(acc[rt][ct][0] + bv, acc[rt][ct][1] + bv);
                pv2.y = pk2(acc[rt][ct][2] + bv, acc[rt][ct][3] + bv);
                *(uint2*)&vT[((size_t)(bidx * HDIM + h) * DHE + d) * KEYS + key] = pv2;
            }
        }
    }
}

// ---------------------------------------------------------------------------
// MFMA flash attention. R15 = exact R12 revert (known-best, attn 73us):
// KVBLK=64 K/V LDS double-buffer, one barrier per chunk, XOR-swizzled
// Ks/Vs, Ps[4][32][72], cvt_pk softmax, Q pre-scale, XCD-local LPT.
// R13 (pad-70 NaN: broke b128 16B alignment) and R14 (K-to-registers:
// compiler spilled kf arrays to scratch — WRITE 49->260MB) both reverted.
// ---------------------------------------------------------------------------
__global__ __launch_bounds__(256, 3) void attn_mfma(
    const unsigned short* __restrict__ qkv,  // [8192][2304] bf16 (Qs,K)
    const unsigned short* __restrict__ vT,   // [4][12][64][2048] bf16
    const int* __restrict__ is_ref,
    unsigned short* __restrict__ ctx)        // [8192][768] bf16
{
    const int g = blockIdx.x;
    const int myx = g & 7, cuu = (g >> 3) & 31, round = g >> 8;
    const int j = round * 32 + ((round & 1) ? (31 - cuu) : cuu); // slot 0..95

    // ---- per-batch ref info ----
    int rmask[4], r4[4];
    #pragma unroll
    for (int bb = 0; bb < 4; bb++) {
        int mask = 0;
        #pragma unroll
        for (int w = 0; w < VDIM; w++)
            if (is_ref[bb * VDIM + w] != 0) mask |= 1 << w;
        rmask[bb] = mask; r4[bb] = __popc(mask);
    }
    // ---- 1. sort batches desc by weight r(8-r) ----
    int ord[4] = {0, 1, 2, 3};
    #pragma unroll
    for (int i = 0; i < 3; i++)
        #pragma unroll
        for (int k = 0; k < 3 - i; k++) {
            const int wa = r4[ord[k]] * (8 - r4[ord[k]]);
            const int wb = r4[ord[k + 1]] * (8 - r4[ord[k + 1]]);
            if (wb > wa) { int tmp = ord[k]; ord[k] = ord[k + 1]; ord[k + 1] = tmp; }
        }
    // ---- 2. snake-deal 48 grps to 8 XCDs; collect my 6 (Gb, Gh) ----
    int Gb[6], Gh[6], ng = 0;
    for (int p = 0; p < 48; p++) {
        const int row = p >> 3, col = p & 7;
        const int x = (row & 1) ? (7 - col) : col;
        if (x == myx) { Gb[ng] = ord[p / 12]; Gh[ng] = p % 12; ng++; }
    }
    // ---- 3. class walk: find j-th task of this XCD (LPT order) ----
    int b = 0, h = 0, half = 0, v = 0, Lsel = 0;
    {
        int jj = j;
        bool found = false;
        for (int o = 8; o >= 0 && !found; o--) {
            for (int gi = 0; gi < 6 && !found; gi++) {
                const int b2 = Gb[gi], r2 = r4[b2];
                const int nv_o = ((8 - r2) == o ? r2 : 0) + (r2 == o ? (8 - r2) : 0);
                const int cnt = 2 * nv_o;
                if (cnt > 0 && jj < cnt) {
                    b = b2; h = Gh[gi]; Lsel = o;
                    half = jj / nv_o;
                    int pos = jj % nv_o;
                    int S = (((8 - r2) == o) ? rmask[b2] : 0)
                          | ((r2 == o) ? ((~rmask[b2]) & 0xff) : 0);
                    for (int vv = 0; vv < 8; vv++)
                        if ((S >> vv) & 1) { if (pos == 0) { v = vv; break; } pos--; }
                    found = true;
                } else jj -= cnt;
            }
        }
    }
    // ------------------------------------------------------

    const int t = threadIdx.x, wave = t >> 6, lane = t & 63;
    const int m = lane & 15, quad = lane >> 4;
    const int n0 = half * 128 + wave * 32;

    __shared__ unsigned short Ks[2][64][64]; // [buf][key][dim], dg' = dg^(key&7)
    __shared__ unsigned short Vs[2][64][64]; // [buf][dim][key], kg' = kg^(dim&7)
    __shared__ unsigned short Ps[4][32][72]; // [wave][query][64-key chunk]

    const int my_ref = (rmask[b] >> v) & 1;
    const unsigned amask = my_ref ? (unsigned)((~rmask[b]) & 0xff)
                                  : (unsigned)rmask[b];
    const int nC = 4 * Lsel;                 // 64-key chunks

    // packed view list: nibble i = i-th set bit of amask
    unsigned vpack = 0;
    {
        unsigned rm = amask; int pi = 0;
        while (rm) { vpack |= (unsigned)(__builtin_ffs((int)rm) - 1) << (4 * pi);
                     rm &= rm - 1; pi++; }
    }

    // Q B-frags: B[n=query=m][k=quad*8+j], two 32-dim K-steps (Q pre-scaled)
    short8 aq[2][2];
    #pragma unroll
    for (int qt = 0; qt < 2; qt++) {
        const size_t row = (size_t)((b * VDIM + v) * NDIM) + n0 + qt * 16 + m;
        #pragma unroll
        for (int ks = 0; ks < 2; ks++)
            aq[qt][ks] = *(const short8*)&qkv[row * C3 + h * DHE + ks * 32 + quad * 8];
    }

    float rs[2] = {0.f, 0.f};     // per-lane l partial, query = qt*16 + m
    float4v O[2][4] = {};

    // staging thread coords: 64 keys/dims, 4 threads each, 2x16B per thread
    const int s_row = t >> 2;                  // key (K) or dim (V), 0..63
    const int s_g   = (t & 3) * 2;             // first 8-short group, 0..7

    const unsigned short* vTb = vT + (size_t)(b * HDIM + h) * DHE * KEYS;
    const unsigned short* qkb = qkv + (size_t)(b * VDIM) * NDIM * C3 + CDIM + h * DHE;

    uint4 kreg[2], vreg[2];

    // chunk c -> view vpack nibble (c>>2), keybase (c&3)*64 within view
    #define LOADC(c)                                                           \
        {                                                                      \
            const int w_ = (int)((vpack >> (((c) >> 2) * 4)) & 15);            \
            const int kb_ = ((c) & 3) * 64;                                    \
            const unsigned short* kp = qkb + (size_t)(w_ * NDIM + kb_ + s_row) * C3; \
            kreg[0] = *(const uint4*)&kp[(s_g + 0) * 8];                       \
            kreg[1] = *(const uint4*)&kp[(s_g + 1) * 8];                       \
            const unsigned short* vp = vTb + (size_t)s_row * KEYS + w_ * NDIM + kb_; \
            vreg[0] = *(const uint4*)&vp[(s_g + 0) * 8];                       \
            vreg[1] = *(const uint4*)&vp[(s_g + 1) * 8];                       \
        }
    #define WRITEC(buf)                                                        \
        {                                                                      \
            *(uint4*)&Ks[buf][s_row][((s_g + 0) ^ (s_row & 7)) * 8] = kreg[0]; \
            *(uint4*)&Ks[buf][s_row][((s_g + 1) ^ (s_row & 7)) * 8] = kreg[1]; \
            *(uint4*)&Vs[buf][s_row][((s_g + 0) ^ (s_row & 7)) * 8] = vreg[0]; \
            *(uint4*)&Vs[buf][s_row][((s_g + 1) ^ (s_row & 7)) * 8] = vreg[1]; \
        }

    if (nC > 0) {
        LOADC(0);
        WRITEC(0);                 // no prior readers; pre-barrier write ok
        if (nC > 1) LOADC(1);
    }

    for (int c = 0; c < nC; c++) {
        const int buf = c & 1;
        __syncthreads();           // chunk c writes visible; buf^1 reads done
        if (c + 1 < nC) {
            WRITEC(buf ^ 1);       // stage chunk c+1 into other buffer
            if (c + 2 < nC) LOADC(c + 2);
        }

        // ---- compute chunk c (64 keys) from buf ----
        #pragma unroll
        for (int kt = 0; kt < 4; kt++) {
            const short8 bk0 = *(const short8*)&Ks[buf][kt * 16 + m][(quad ^ (m & 7)) * 8];
            const short8 bk1 = *(const short8*)&Ks[buf][kt * 16 + m][((4 + quad) ^ (m & 7)) * 8];
            #pragma unroll
            for (int qt = 0; qt < 2; qt++) {
                float4v s = {};
                s = __builtin_amdgcn_mfma_f32_16x16x32_bf16(bk0, aq[qt][0], s, 0, 0, 0);
                s = __builtin_amdgcn_mfma_f32_16x16x32_bf16(bk1, aq[qt][1], s, 0, 0, 0);
                // s[r]: key = kt*16 + quad*4 + r, query = qt*16 + m
                const float p0 = __builtin_amdgcn_exp2f(s[0]);
                const float p1 = __builtin_amdgcn_exp2f(s[1]);
                const float p2 = __builtin_amdgcn_exp2f(s[2]);
                const float p3 = __builtin_amdgcn_exp2f(s[3]);
                rs[qt] += (p0 + p1) + (p2 + p3);
                uint2 pw;
                pw.x = pk2(p0, p1);
                pw.y = pk2(p2, p3);
                *(uint2*)&Ps[wave][qt * 16 + m][kt * 16 + quad * 4] = pw;
            }
        }
        #pragma unroll
        for (int kk = 0; kk < 2; kk++) {
            const short8 ap0 = *(const short8*)&Ps[wave][m][kk * 32 + quad * 8];
            const short8 ap1 = *(const short8*)&Ps[wave][16 + m][kk * 32 + quad * 8];
            #pragma unroll
            for (int ct = 0; ct < 4; ct++) {
                const short8 bv = *(const short8*)&Vs[buf][ct * 16 + m]
                    [((kk * 4 + quad) ^ (m & 7)) * 8];
                O[0][ct] = __builtin_amdgcn_mfma_f32_16x16x32_bf16(ap0, bv, O[0][ct], 0, 0, 0);
                O[1][ct] = __builtin_amdgcn_mfma_f32_16x16x32_bf16(ap1, bv, O[1][ct], 0, 0, 0);
            }
        }
    }
    #undef LOADC
    #undef WRITEC

    // final: reduce l across the 4 quad-copies, broadcast to O rows, write
    #pragma unroll
    for (int qt = 0; qt < 2; qt++) {
        float x = rs[qt];
        x += __shfl_xor(x, 16, 64);
        x += __shfl_xor(x, 32, 64);
        const float inv = (x > 0.f) ? 1.f / x : 0.f;   // query = qt*16 + m
        float invq[4];
        #pragma unroll
        for (int r = 0; r < 4; r++)
            invq[r] = __shfl(inv, quad * 4 + r, 64);   // query = quad*4+r
        const size_t rowg = (size_t)((b * VDIM + v) * NDIM) + n0 + qt * 16 + quad * 4;
        #pragma unroll
        for (int ct = 0; ct < 4; ct++) {
            const int cc = h * DHE + ct * 16 + m;
            const unsigned u01 = pk2(O[qt][ct][0] * invq[0], O[qt][ct][1] * invq[1]);
            const unsigned u23 = pk2(O[qt][ct][2] * invq[2], O[qt][ct][3] * invq[3]);
            ctx[(rowg + 0) * CDIM + cc] = (unsigned short)u01;
            ctx[(rowg + 1) * CDIM + cc] = (unsigned short)(u01 >> 16);
            ctx[(rowg + 2) * CDIM + cc] = (unsigned short)u23;
            ctx[(rowg + 3) * CDIM + cc] = (unsigned short)(u23 >> 16);
        }
    }
}

// ---------------------------------------------------------------------------
// Out-proj GEMM. BK=64 twin-buffer + XCD swizzle; fp32 out + passthrough.
// ---------------------------------------------------------------------------
__global__ __launch_bounds__(256) void gemm_out_mfma(
    const unsigned short* __restrict__ A,   // ctx_b [8192][768] bf16
    const unsigned short* __restrict__ W,   // w_out bf16 [768][768]
    const float* __restrict__ bias,
    const float* __restrict__ feats,
    const int* __restrict__ is_ref,
    float* __restrict__ out)                // [8192][768] fp32
{
    __shared__ __attribute__((aligned(16))) unsigned short As[2][128][32];
    __shared__ __attribute__((aligned(16))) unsigned short Ws[2][128][32];
    const int t = threadIdx.x;
    const int wave = t >> 6, lane = t & 63;
    const int m = lane & 15, quad = lane >> 4;
    const int wr = (wave >> 1) * 64, wc = (wave & 1) * 64;

    const int lin = blockIdx.y * gridDim.x + blockIdx.x;
    const int cpx = (gridDim.x * gridDim.y) >> 3;
    const int swz = (lin & 7) * cpx + (lin >> 3);
    const int row0 = (swz / gridDim.x) * 128, col0 = (swz % gridDim.x) * 128;

    const int sr = t >> 2, sk = (t & 3) * 8;
    const unsigned short* ag = &A[(size_t)(row0 + sr) * CDIM + sk];
    const unsigned short* wg = &W[(size_t)(col0 + sr) * CDIM + sk];

    float4v acc[4][4] = {};

    for (int k0 = 0; k0 < CDIM; k0 += 64) {
        #pragma unroll
        for (int ks = 0; ks < 2; ks++) {
            gld_lds16(ag + k0 + ks * 32, &As[ks][sr][sk]);
            gld_lds16(ag + (size_t)64 * CDIM + k0 + ks * 32, &As[ks][64 + sr][sk]);
            gld_lds16(wg + k0 + ks * 32, &Ws[ks][sr][sk]);
            gld_lds16(wg + (size_t)64 * CDIM + k0 + ks * 32, &Ws[ks][64 + sr][sk]);
        }
        __syncthreads();
        #pragma unroll
        for (int ks = 0; ks < 2; ks++) {
            short8 a[4], b[4];
            #pragma unroll
            for (int rt = 0; rt < 4; rt++)
                a[rt] = *(const short8*)&As[ks][wr + rt * 16 + m][quad * 8];
            #pragma unroll
            for (int ct = 0; ct < 4; ct++)
                b[ct] = *(const short8*)&Ws[ks][wc + ct * 16 + m][quad * 8];
            #pragma unroll
            for (int rt = 0; rt < 4; rt++)
                #pragma unroll
                for (int ct = 0; ct < 4; ct++)
                    acc[rt][ct] = __builtin_amdgcn_mfma_f32_16x16x32_bf16(
                        a[rt], b[ct], acc[rt][ct], 0, 0, 0);
        }
        __syncthreads();
    }

    const int bidx = row0 / (VDIM * NDIM);
    const int vidx = (row0 / NDIM) % VDIM;
    const int my = is_ref[bidx * VDIM + vidx];
    bool has = false;
    #pragma unroll
    for (int w = 0; w < VDIM; w++) has = has || (is_ref[bidx * VDIM + w] != my);

    #pragma unroll
    for (int ct = 0; ct < 4; ct++) {
        const int col = col0 + wc + ct * 16 + m;
        const float bv = bias[col];
        #pragma unroll
        for (int rt = 0; rt < 4; rt++) {
            const size_t row = (size_t)row0 + wr + rt * 16 + quad * 4;
            #pragma unroll
            for (int r = 0; r < 4; r++) {
                float o = acc[rt][ct][r] + bv;
                if (!has) o = feats[(row + r) * CDIM + col];
                out[(row + r) * CDIM + col] = o;
            }
        }
    }
}

extern "C" void kernel_launch(void* const* d_in, const int* in_sizes, int n_in,
                              void* d_out, int out_size, void* d_ws, size_t ws_size,
                              hipStream_t stream) {
    const float* feats = (const float*)d_in[0];
    const int*   is_ref = (const int*)d_in[1];
    const float* w_qkv = (const float*)d_in[2];
    const float* b_qkv = (const float*)d_in[3];
    const float* w_out = (const float*)d_in[4];
    const float* b_out = (const float*)d_in[5];
    float* out = (float*)d_out;

    unsigned short* qkv_b = (unsigned short*)d_ws;                 // 8192x2304
    unsigned short* vT    = qkv_b + (size_t)ROWS * C3;             // 4x12x64x2048
    unsigned short* ctx_b = vT + (size_t)BDIM * HDIM * DHE * KEYS; // 8192x768
    unsigned short* A_bf  = ctx_b + (size_t)ROWS * CDIM;           // 8192x768
    unsigned short* Wq_bf = A_bf + (size_t)ROWS * CDIM;            // 2304x768
    unsigned short* Wo_bf = Wq_bf + (size_t)C3 * CDIM;             // 768x768

    cast_bf16_all<<<dim3((NA8 + NW8 + NO8) / 256), 256, 0, stream>>>(
        feats, w_qkv, w_out, A_bf, Wq_bf, Wo_bf);

    dim3 g1(C3 / 128, ROWS / 128);                                 // 18 x 64
    gemm_qkv_mfma<<<g1, 256, 0, stream>>>(A_bf, Wq_bf, b_qkv, qkv_b, vT);

    attn_mfma<<<dim3(768), 256, 0, stream>>>(qkv_b, vT, is_ref, ctx_b);

    dim3 g3(CDIM / 128, ROWS / 128);                               // 6 x 64
    gemm_out_mfma<<<g3, 256, 0, stream>>>(ctx_b, Wo_bf, b_out, feats, is_ref, out);
    (void)in_sizes; (void)n_in; (void)out_size; (void)ws_size;
}